// Round 1
// baseline (1133.518 us; speedup 1.0000x reference)
//
#include <hip/hip_runtime.h>
#include <math.h>

#define BATCH 4
#define SEQ   4096
#define EMB   1024
#define HD    128
#define MROWS (BATCH*SEQ)

// ---------------- QKV projection ----------------
// grid: MROWS/QROWS blocks, 128 threads. Each block: QROWS rows x 128 cols x {q,k,v}.
// Each LDS-broadcast x value feeds 3 FMAs (q,k,v) -> ~balanced VALU vs LDS pipes.
#define QROWS 8

__global__ __launch_bounds__(128) void qkv_kernel(
    const float* __restrict__ x,
    const float* __restrict__ Wq, const float* __restrict__ Wk, const float* __restrict__ Wv,
    float* __restrict__ q, float* __restrict__ k, float* __restrict__ v)
{
    // pad 132: rows 16B-aligned (b128-mergeable reads), writes conflict-free
    __shared__ __align__(16) float xs[QROWS][132];
    const int tid = threadIdx.x;           // = output column 0..127
    const int m0  = blockIdx.x * QROWS;

    float aq[QROWS], ak[QROWS], av[QROWS];
#pragma unroll
    for (int i = 0; i < QROWS; ++i) { aq[i] = 0.f; ak[i] = 0.f; av[i] = 0.f; }

    for (int kt = 0; kt < EMB; kt += 128) {
        __syncthreads();
#pragma unroll
        for (int i = 0; i < QROWS; ++i)
            xs[i][tid] = x[(size_t)(m0 + i) * EMB + kt + tid];
        __syncthreads();
#pragma unroll 4
        for (int kk = 0; kk < 128; ++kk) {
            float wq = Wq[(size_t)(kt + kk) * HD + tid];
            float wk = Wk[(size_t)(kt + kk) * HD + tid];
            float wv = Wv[(size_t)(kt + kk) * HD + tid];
#pragma unroll
            for (int i = 0; i < QROWS; ++i) {
                float xv = xs[i][kk];
                aq[i] = fmaf(xv, wq, aq[i]);
                ak[i] = fmaf(xv, wk, ak[i]);
                av[i] = fmaf(xv, wv, av[i]);
            }
        }
    }
#pragma unroll
    for (int i = 0; i < QROWS; ++i) {
        q[(size_t)(m0 + i) * HD + tid] = aq[i];
        k[(size_t)(m0 + i) * HD + tid] = ak[i];
        v[(size_t)(m0 + i) * HD + tid] = av[i];
    }
}

// ---------------- Flash attention (causal, online softmax) ----------------
#define BQ 32
#define BK 32
#define PAD 132   // floats per LDS row for Q/K/V tiles (16B aligned)
#define SPAD 33   // floats per LDS row for the score tile

__global__ __launch_bounds__(256) void flash_kernel(
    const float* __restrict__ q, const float* __restrict__ k,
    const float* __restrict__ v, float* __restrict__ out)
{
    __shared__ __align__(16) float Qs[BQ * PAD];
    __shared__ __align__(16) float KVs[BK * PAD];
    __shared__ float Ss[BQ * SPAD];
    __shared__ float mrow[BQ], lrow[BQ], arow[BQ];

    const int tid = threadIdx.x;
    const int qi  = (int)(gridDim.x - 1 - blockIdx.x);  // reversed: big tiles first
    const int b   = blockIdx.y;
    const int q0  = qi * BQ;
    const float scale = 0.08838834764831844f; // 1/sqrt(128)

    // ---- load Q tile (rows contiguous: 32*128 floats) ----
    const float4* Q4 = (const float4*)(q + ((size_t)b * SEQ + q0) * HD);
#pragma unroll
    for (int i = 0; i < 4; ++i) {
        int g  = tid + 256 * i;      // 0..1023 float4s
        int r  = g >> 5;             // 32 float4 per row
        int c4 = g & 31;
        *(float4*)&Qs[r * PAD + c4 * 4] = Q4[g];
    }
    if (tid < BQ) { mrow[tid] = -1e30f; lrow[tid] = 0.f; }

    // PV / output mapping: rows 4*tz..+3, cols 4*tw..+3
    const int tz = tid >> 5;   // 0..7
    const int tw = tid & 31;   // 0..31
    float O[4][4];
#pragma unroll
    for (int i = 0; i < 4; ++i)
#pragma unroll
        for (int j = 0; j < 4; ++j) O[i][j] = 0.f;

    // S-phase mapping: rows 2*ty..+1, cols 2*tx..+1
    const int ty = tid >> 4;   // 0..15
    const int tx = tid & 15;   // 0..15

    for (int j0 = 0; j0 <= qi; ++j0) {
        const float4* K4 = (const float4*)(k + ((size_t)b * SEQ + j0 * BK) * HD);
        __syncthreads();   // previous PV done reading KVs/Ss
#pragma unroll
        for (int i = 0; i < 4; ++i) {
            int g = tid + 256 * i;
            int r = g >> 5, c4 = g & 31;
            *(float4*)&KVs[r * PAD + c4 * 4] = K4[g];
        }
        __syncthreads();

        // ---- S = Q K^T (2x2 micro-tile per thread, float4 over k-dim) ----
        float s00 = 0.f, s01 = 0.f, s10 = 0.f, s11 = 0.f;
#pragma unroll 8
        for (int kk = 0; kk < HD; kk += 4) {
            float4 qa = *(const float4*)&Qs[(2 * ty    ) * PAD + kk];
            float4 qb = *(const float4*)&Qs[(2 * ty + 1) * PAD + kk];
            float4 ka = *(const float4*)&KVs[(2 * tx    ) * PAD + kk];
            float4 kb = *(const float4*)&KVs[(2 * tx + 1) * PAD + kk];
            s00 = fmaf(qa.x, ka.x, s00); s00 = fmaf(qa.y, ka.y, s00);
            s00 = fmaf(qa.z, ka.z, s00); s00 = fmaf(qa.w, ka.w, s00);
            s01 = fmaf(qa.x, kb.x, s01); s01 = fmaf(qa.y, kb.y, s01);
            s01 = fmaf(qa.z, kb.z, s01); s01 = fmaf(qa.w, kb.w, s01);
            s10 = fmaf(qb.x, ka.x, s10); s10 = fmaf(qb.y, ka.y, s10);
            s10 = fmaf(qb.z, ka.z, s10); s10 = fmaf(qb.w, ka.w, s10);
            s11 = fmaf(qb.x, kb.x, s11); s11 = fmaf(qb.y, kb.y, s11);
            s11 = fmaf(qb.z, kb.z, s11); s11 = fmaf(qb.w, kb.w, s11);
        }
        Ss[(2 * ty    ) * SPAD + 2 * tx    ] = s00;
        Ss[(2 * ty    ) * SPAD + 2 * tx + 1] = s01;
        Ss[(2 * ty + 1) * SPAD + 2 * tx    ] = s10;
        Ss[(2 * ty + 1) * SPAD + 2 * tx + 1] = s11;
        __syncthreads();

        // prefetch V into registers (overlaps softmax below)
        const float4* V4 = (const float4*)(v + ((size_t)b * SEQ + j0 * BK) * HD);
        float4 vreg[4];
#pragma unroll
        for (int i = 0; i < 4; ++i) vreg[i] = V4[tid + 256 * i];

        // ---- online softmax: one thread per row ----
        if (tid < BQ) {
            int r = tid;
            int cmax = q0 + r - j0 * BK + 1;          // valid cols [0, cmax)
            cmax = (cmax > BK) ? BK : cmax;           // >=1 always (j0 <= qi)
            float mx = mrow[r];
            float oldm = mx;
#pragma unroll
            for (int c = 0; c < BK; ++c) {
                float sv = Ss[r * SPAD + c] * scale;
                sv = (c < cmax) ? sv : -1e30f;
                mx = fmaxf(mx, sv);
            }
            float al = __expf(oldm - mx);
            float sum = 0.f;
#pragma unroll
            for (int c = 0; c < BK; ++c) {
                float sv = Ss[r * SPAD + c] * scale;
                float p = (c < cmax) ? __expf(sv - mx) : 0.f;
                Ss[r * SPAD + c] = p;
                sum += p;
            }
            mrow[r] = mx;
            lrow[r] = lrow[r] * al + sum;
            arow[r] = al;
        }

        // write V into KVs (K no longer needed; softmax uses Ss only)
#pragma unroll
        for (int i = 0; i < 4; ++i) {
            int g = tid + 256 * i;
            int r = g >> 5, c4 = g & 31;
            *(float4*)&KVs[r * PAD + c4 * 4] = vreg[i];
        }
        __syncthreads();

        // ---- rescale O, then O += P @ V ----
        float al[4];
#pragma unroll
        for (int i = 0; i < 4; ++i) al[i] = arow[4 * tz + i];
#pragma unroll
        for (int i = 0; i < 4; ++i) {
            O[i][0] *= al[i]; O[i][1] *= al[i]; O[i][2] *= al[i]; O[i][3] *= al[i];
        }
#pragma unroll 4
        for (int j = 0; j < BK; ++j) {
            float4 vv = *(const float4*)&KVs[j * PAD + 4 * tw];
            float p0 = Ss[(4 * tz + 0) * SPAD + j];
            float p1 = Ss[(4 * tz + 1) * SPAD + j];
            float p2 = Ss[(4 * tz + 2) * SPAD + j];
            float p3 = Ss[(4 * tz + 3) * SPAD + j];
            O[0][0] = fmaf(p0, vv.x, O[0][0]); O[0][1] = fmaf(p0, vv.y, O[0][1]);
            O[0][2] = fmaf(p0, vv.z, O[0][2]); O[0][3] = fmaf(p0, vv.w, O[0][3]);
            O[1][0] = fmaf(p1, vv.x, O[1][0]); O[1][1] = fmaf(p1, vv.y, O[1][1]);
            O[1][2] = fmaf(p1, vv.z, O[1][2]); O[1][3] = fmaf(p1, vv.w, O[1][3]);
            O[2][0] = fmaf(p2, vv.x, O[2][0]); O[2][1] = fmaf(p2, vv.y, O[2][1]);
            O[2][2] = fmaf(p2, vv.z, O[2][2]); O[2][3] = fmaf(p2, vv.w, O[2][3]);
            O[3][0] = fmaf(p3, vv.x, O[3][0]); O[3][1] = fmaf(p3, vv.y, O[3][1]);
            O[3][2] = fmaf(p3, vv.z, O[3][2]); O[3][3] = fmaf(p3, vv.w, O[3][3]);
        }
    }

    // ---- epilogue: O / l, store ----
    float* outp = out + ((size_t)b * SEQ + q0) * HD;
#pragma unroll
    for (int i = 0; i < 4; ++i) {
        float linv = 1.0f / lrow[4 * tz + i];
        float4 res;
        res.x = O[i][0] * linv; res.y = O[i][1] * linv;
        res.z = O[i][2] * linv; res.w = O[i][3] * linv;
        *(float4*)&outp[(size_t)(4 * tz + i) * HD + 4 * tw] = res;
    }
}

extern "C" void kernel_launch(void* const* d_in, const int* in_sizes, int n_in,
                              void* d_out, int out_size, void* d_ws, size_t ws_size,
                              hipStream_t stream) {
    const float* x  = (const float*)d_in[0];
    const float* Wq = (const float*)d_in[1];
    const float* Wk = (const float*)d_in[2];
    const float* Wv = (const float*)d_in[3];

    float* q = (float*)d_ws;                    // 3 * 16384*128 floats = 25.2 MB
    float* k = q + (size_t)MROWS * HD;
    float* v = k + (size_t)MROWS * HD;
    float* out = (float*)d_out;

    qkv_kernel<<<dim3(MROWS / QROWS), dim3(128), 0, stream>>>(x, Wq, Wk, Wv, q, k, v);
    flash_kernel<<<dim3(SEQ / BQ, BATCH), dim3(256), 0, stream>>>(q, k, v, out);
}

// Round 2
// 255.453 us; speedup vs baseline: 4.4373x; 4.4373x over previous
//
#include <hip/hip_runtime.h>
#include <math.h>

#define BATCH 4
#define SEQ   4096
#define EMB   1024
#define HD    128
#define MROWS (BATCH*SEQ)
#define SCALE 0.08838834764831844f   // 1/sqrt(128)

typedef __attribute__((ext_vector_type(8))) short bf16x8;   // MFMA A/B frag (4 VGPR)
typedef __attribute__((ext_vector_type(4))) short short4v;  // 8B LDS store
typedef __attribute__((ext_vector_type(4))) float f32x4;    // MFMA C/D frag
typedef __attribute__((ext_vector_type(4))) int   i32x4;    // 16B copy

static __device__ __forceinline__ unsigned short f2bf(float f) {
    unsigned int u = __float_as_uint(f);
    u += 0x7fff + ((u >> 16) & 1);       // RNE
    return (unsigned short)(u >> 16);
}
static __device__ __forceinline__ unsigned int f2bf2(float lo, float hi) {
    return (unsigned int)f2bf(lo) | ((unsigned int)f2bf(hi) << 16);
}

// ---------------- W transpose + bf16 (+ fold q-scale) ----------------
// Wt_w[n=128][k=1024] bf16 from W[k=1024][n=128] fp32.  grid (16,3) x 128 thr.
__global__ __launch_bounds__(128) void wtrans_kernel(
    const float* __restrict__ Wq, const float* __restrict__ Wk,
    const float* __restrict__ Wv, unsigned short* __restrict__ Wt)
{
    const int w  = blockIdx.y;
    const float* W = (w == 0) ? Wq : (w == 1) ? Wk : Wv;
    const float sc = (w == 0) ? SCALE : 1.0f;
    unsigned short* dst = Wt + (size_t)w * 131072;
    const int n  = threadIdx.x;
    const int k0 = blockIdx.x * 64;
    for (int jc = 0; jc < 8; ++jc) {
        float v[8];
#pragma unroll
        for (int je = 0; je < 8; ++je)
            v[je] = W[(size_t)(k0 + jc * 8 + je) * HD + n] * sc;
        i32x4 p;
        p[0] = f2bf2(v[0], v[1]); p[1] = f2bf2(v[2], v[3]);
        p[2] = f2bf2(v[4], v[5]); p[3] = f2bf2(v[6], v[7]);
        *(i32x4*)&dst[(size_t)n * 1024 + k0 + jc * 8] = p;
    }
}

// ---------------- QKV projection via MFMA ----------------
// grid (3, 128): x = which W, y = row tile (128 rows).  256 thr = 4 waves (2x2 of 64x64).
__global__ __launch_bounds__(256) void qkv_kernel(
    const float* __restrict__ x, const unsigned short* __restrict__ Wt,
    unsigned short* __restrict__ qb, unsigned short* __restrict__ kb,
    unsigned short* __restrict__ vtb)
{
    __shared__ unsigned short lds[2 * 128 * 72];
    unsigned short* As = lds;              // x tile   128(m) x 64(k), pad 72
    unsigned short* Bs = lds + 128 * 72;   // Wt tile  128(n) x 64(k), pad 72

    const int w   = blockIdx.x;
    const int m0  = blockIdx.y * 128;
    const unsigned short* Wm = Wt + (size_t)w * 131072;
    const int t    = threadIdx.x;
    const int lane = t & 63, wv = t >> 6;
    const int quad = lane >> 4, l16 = lane & 15;
    const int mhalf = wv >> 1, nhalf = wv & 1;

    f32x4 acc[4][4];
#pragma unroll
    for (int i = 0; i < 4; ++i)
#pragma unroll
        for (int j = 0; j < 4; ++j) acc[i][j] = (f32x4){0.f, 0.f, 0.f, 0.f};

    const int r  = t >> 1;            // 0..127 (row for A, n for B)
    const int ch = (t & 1) * 32;

    for (int kt = 0; kt < EMB; kt += 64) {
        __syncthreads();
        // stage A: x fp32 -> bf16
#pragma unroll
        for (int i = 0; i < 4; ++i) {
            const float* px = &x[(size_t)(m0 + r) * EMB + kt + ch + i * 8];
            float4 a = *(const float4*)px;
            float4 b = *(const float4*)(px + 4);
            i32x4 p;
            p[0] = f2bf2(a.x, a.y); p[1] = f2bf2(a.z, a.w);
            p[2] = f2bf2(b.x, b.y); p[3] = f2bf2(b.z, b.w);
            *(i32x4*)&As[r * 72 + ch + i * 8] = p;
        }
        // stage B: Wt bf16 direct
#pragma unroll
        for (int i = 0; i < 4; ++i)
            *(i32x4*)&Bs[r * 72 + ch + i * 8] =
                *(const i32x4*)&Wm[(size_t)r * 1024 + kt + ch + i * 8];
        __syncthreads();
#pragma unroll
        for (int ks = 0; ks < 2; ++ks) {
            bf16x8 aA[4], aB[4];
#pragma unroll
            for (int mt = 0; mt < 4; ++mt)
                aA[mt] = *(const bf16x8*)&As[(mhalf * 64 + mt * 16 + l16) * 72 + ks * 32 + quad * 8];
#pragma unroll
            for (int nt = 0; nt < 4; ++nt)
                aB[nt] = *(const bf16x8*)&Bs[(nhalf * 64 + nt * 16 + l16) * 72 + ks * 32 + quad * 8];
#pragma unroll
            for (int mt = 0; mt < 4; ++mt)
#pragma unroll
                for (int nt = 0; nt < 4; ++nt)
                    acc[mt][nt] = __builtin_amdgcn_mfma_f32_16x16x32_bf16(
                        aA[mt], aB[nt], acc[mt][nt], 0, 0, 0);
        }
    }

    // epilogue: C -> LDS (layout per output), then coalesced copy out
    __syncthreads();
    unsigned short* Cs = lds;   // 128x128 bf16 = 16384 shorts
    if (w < 2) {
        // natural [s][h]
#pragma unroll
        for (int mt = 0; mt < 4; ++mt)
#pragma unroll
            for (int nt = 0; nt < 4; ++nt)
#pragma unroll
                for (int rr = 0; rr < 4; ++rr)
                    Cs[(mhalf * 64 + mt * 16 + quad * 4 + rr) * 128 +
                       nhalf * 64 + nt * 16 + l16] = f2bf(acc[mt][nt][rr]);
    } else {
        // transposed [h][s] (4 consecutive s per lane -> b64)
#pragma unroll
        for (int mt = 0; mt < 4; ++mt)
#pragma unroll
            for (int nt = 0; nt < 4; ++nt) {
                short4v p;
                p[0] = (short)f2bf(acc[mt][nt][0]); p[1] = (short)f2bf(acc[mt][nt][1]);
                p[2] = (short)f2bf(acc[mt][nt][2]); p[3] = (short)f2bf(acc[mt][nt][3]);
                *(short4v*)&Cs[(nhalf * 64 + nt * 16 + l16) * 128 +
                               mhalf * 64 + mt * 16 + quad * 4] = p;
            }
    }
    __syncthreads();
    if (w < 2) {
        unsigned short* dst = ((w == 0) ? qb : kb) + (size_t)m0 * HD;
#pragma unroll
        for (int i = 0; i < 8; ++i) {
            int g = i * 256 + t;
            *(i32x4*)&dst[g * 8] = *(const i32x4*)&Cs[g * 8];
        }
    } else {
        const int b = m0 >> 12, s0 = m0 & 4095;
#pragma unroll
        for (int i = 0; i < 8; ++i) {
            int g = i * 256 + t;
            int row = g >> 4, col = (g & 15) * 8;
            *(i32x4*)&vtb[(size_t)b * (HD * SEQ) + (size_t)row * SEQ + s0 + col] =
                *(const i32x4*)&Cs[row * 128 + col];
        }
    }
}

// ---------------- Flash attention, MFMA (S^T formulation) ----------------
// BQ=32 (2 waves x 16 qrows), BK=64.  grid (128, 4), 128 thr.
// S^T = K.Q^T  (A=K frag, B=Q frag, both row-major contiguous)
// O^T = V^T.P^T (A=Vt frag, B=Pt frag) -> lane owns qrow = lane&15 everywhere.
#define PADK 136   // 64 x 136 bf16
#define PADV 72    // 128 x 72 bf16
#define PADP 72    // 32 x 72 bf16

__global__ __launch_bounds__(128) void flash_kernel(
    const unsigned short* __restrict__ qb, const unsigned short* __restrict__ kb,
    const unsigned short* __restrict__ vtb, float* __restrict__ out)
{
    __shared__ unsigned short Ks[64 * PADK];
    __shared__ unsigned short Vt[128 * PADV];
    __shared__ unsigned short Pt[32 * PADP];

    const int t    = threadIdx.x;
    const int lane = t & 63, w = t >> 6;
    const int quad = lane >> 4, l16 = lane & 15;
    const int b    = blockIdx.y;
    const int qi   = 127 - (int)blockIdx.x;       // big tiles first
    const int qrow = qi * 32 + w * 16 + l16;      // within-batch q row of this lane
    const int jmax = (qi * 32 + 31) / 64 + 1;

    // Q fragments (B-operand) live in registers for the whole kernel
    bf16x8 qf[4];
    {
        const unsigned short* qp = qb + ((size_t)b * SEQ + qrow) * HD;
#pragma unroll
        for (int ks = 0; ks < 4; ++ks)
            qf[ks] = *(const bf16x8*)&qp[ks * 32 + quad * 8];
    }

    f32x4 O[8];
#pragma unroll
    for (int i = 0; i < 8; ++i) O[i] = (f32x4){0.f, 0.f, 0.f, 0.f};
    float m_run = -1e30f, l_run = 0.f;

    const unsigned short* kbb  = kb  + (size_t)b * SEQ * HD;
    const unsigned short* vtbb = vtb + (size_t)b * HD * SEQ;

    for (int j0 = 0; j0 < jmax; ++j0) {
        // ---- stage K tile (contiguous 16 KB) and Vt tile ----
#pragma unroll
        for (int i = 0; i < 8; ++i) {
            int g = i * 128 + t;
            i32x4 kd = *(const i32x4*)&kbb[(size_t)j0 * 64 * HD + g * 8];
            *(i32x4*)&Ks[(g >> 4) * PADK + (g & 15) * 8] = kd;
        }
#pragma unroll
        for (int i = 0; i < 8; ++i) {
            int h = i * 16 + (t >> 3), s8 = t & 7;
            i32x4 vd = *(const i32x4*)&vtbb[(size_t)h * SEQ + j0 * 64 + s8 * 8];
            *(i32x4*)&Vt[h * PADV + s8 * 8] = vd;
        }
        __syncthreads();

        // ---- S^T = K . Q^T  (4 kv m-tiles x 4 k-steps) ----
        f32x4 st[4];
#pragma unroll
        for (int mt = 0; mt < 4; ++mt) {
            f32x4 a = (f32x4){0.f, 0.f, 0.f, 0.f};
#pragma unroll
            for (int ks = 0; ks < 4; ++ks) {
                bf16x8 kf = *(const bf16x8*)&Ks[(mt * 16 + l16) * PADK + ks * 32 + quad * 8];
                a = __builtin_amdgcn_mfma_f32_16x16x32_bf16(kf, qf[ks], a, 0, 0, 0);
            }
            st[mt] = a;
        }

        // ---- causal mask (wave-uniform skip when tile fully valid) ----
        if (j0 * 64 + 63 > qi * 32 + w * 16) {
#pragma unroll
            for (int mt = 0; mt < 4; ++mt)
#pragma unroll
                for (int rr = 0; rr < 4; ++rr) {
                    int kv = j0 * 64 + mt * 16 + quad * 4 + rr;
                    if (kv > qrow) st[mt][rr] = -1e30f;
                }
        }

        // ---- online softmax: lane owns one q-row; reduce in-lane + quads ----
        float mx = -1e30f;
#pragma unroll
        for (int mt = 0; mt < 4; ++mt)
#pragma unroll
            for (int rr = 0; rr < 4; ++rr) mx = fmaxf(mx, st[mt][rr]);
        mx = fmaxf(mx, __shfl_xor(mx, 16));
        mx = fmaxf(mx, __shfl_xor(mx, 32));
        const float m_new = fmaxf(m_run, mx);
        const float alpha = __expf(m_run - m_new);
        float psum = 0.f;
#pragma unroll
        for (int mt = 0; mt < 4; ++mt)
#pragma unroll
            for (int rr = 0; rr < 4; ++rr) {
                float p = __expf(st[mt][rr] - m_new);   // masked -> exp(-huge) = 0
                st[mt][rr] = p;
                psum += p;
            }
        psum += __shfl_xor(psum, 16);
        psum += __shfl_xor(psum, 32);
        m_run = m_new;
        l_run = l_run * alpha + psum;

        // ---- P^T -> LDS (wave-private rows; 4 consecutive kv per b64) ----
#pragma unroll
        for (int mt = 0; mt < 4; ++mt) {
            short4v p;
            p[0] = (short)f2bf(st[mt][0]); p[1] = (short)f2bf(st[mt][1]);
            p[2] = (short)f2bf(st[mt][2]); p[3] = (short)f2bf(st[mt][3]);
            *(short4v*)&Pt[(w * 16 + l16) * PADP + mt * 16 + quad * 4] = p;
        }

        // ---- rescale O ----
#pragma unroll
        for (int i = 0; i < 8; ++i) {
            O[i][0] *= alpha; O[i][1] *= alpha; O[i][2] *= alpha; O[i][3] *= alpha;
        }

        // ---- O^T += V^T . P^T  (8 head m-tiles x 2 k-steps) ----
        bf16x8 pf0 = *(const bf16x8*)&Pt[(w * 16 + l16) * PADP + quad * 8];
        bf16x8 pf1 = *(const bf16x8*)&Pt[(w * 16 + l16) * PADP + 32 + quad * 8];
#pragma unroll
        for (int mt = 0; mt < 8; ++mt) {
            bf16x8 vf0 = *(const bf16x8*)&Vt[(mt * 16 + l16) * PADV + quad * 8];
            bf16x8 vf1 = *(const bf16x8*)&Vt[(mt * 16 + l16) * PADV + 32 + quad * 8];
            O[mt] = __builtin_amdgcn_mfma_f32_16x16x32_bf16(vf0, pf0, O[mt], 0, 0, 0);
            O[mt] = __builtin_amdgcn_mfma_f32_16x16x32_bf16(vf1, pf1, O[mt], 0, 0, 0);
        }
        __syncthreads();   // protect Ks/Vt before next stage
    }

    // ---- epilogue ----
    const float linv = 1.0f / l_run;
    float* op = out + ((size_t)b * SEQ + qrow) * HD;
#pragma unroll
    for (int mt = 0; mt < 8; ++mt) {
        float4 res;
        res.x = O[mt][0] * linv; res.y = O[mt][1] * linv;
        res.z = O[mt][2] * linv; res.w = O[mt][3] * linv;
        *(float4*)&op[mt * 16 + quad * 4] = res;
    }
}

extern "C" void kernel_launch(void* const* d_in, const int* in_sizes, int n_in,
                              void* d_out, int out_size, void* d_ws, size_t ws_size,
                              hipStream_t stream) {
    const float* x  = (const float*)d_in[0];
    const float* Wq = (const float*)d_in[1];
    const float* Wk = (const float*)d_in[2];
    const float* Wv = (const float*)d_in[3];

    unsigned short* qb  = (unsigned short*)d_ws;           // [16384][128] bf16
    unsigned short* kb  = qb  + (size_t)MROWS * HD;        // [16384][128] bf16
    unsigned short* vtb = kb  + (size_t)MROWS * HD;        // [4][128][4096] bf16
    unsigned short* Wt  = vtb + (size_t)MROWS * HD;        // [3][128][1024] bf16
    float* out = (float*)d_out;

    wtrans_kernel<<<dim3(16, 3),  dim3(128), 0, stream>>>(Wq, Wk, Wv, Wt);
    qkv_kernel  <<<dim3(3, 128),  dim3(256), 0, stream>>>(x, Wt, qb, kb, vtb);
    flash_kernel<<<dim3(128, 4),  dim3(128), 0, stream>>>(qb, kb, vtb, out);
}

// Round 3
// 206.942 us; speedup vs baseline: 5.4775x; 1.2344x over previous
//
#include <hip/hip_runtime.h>
#include <math.h>

#define BATCH 4
#define SEQ   4096
#define EMB   1024
#define HD    128
#define MROWS (BATCH*SEQ)
#define SCALE 0.08838834764831844f   // 1/sqrt(128)
#define NQT   128                    // q-tiles per batch (32 rows each)
#define MAXC  4                      // max KV chunks (1024 each) per q-tile

typedef __attribute__((ext_vector_type(8))) short bf16x8;   // MFMA A/B frag (4 VGPR)
typedef __attribute__((ext_vector_type(4))) short short4v;  // 8B LDS store
typedef __attribute__((ext_vector_type(4))) float f32x4;    // MFMA C/D frag
typedef __attribute__((ext_vector_type(4))) int   i32x4;    // 16B copy

static __device__ __forceinline__ unsigned short f2bf(float f) {
    unsigned int u = __float_as_uint(f);
    u += 0x7fff + ((u >> 16) & 1);       // RNE
    return (unsigned short)(u >> 16);
}
static __device__ __forceinline__ unsigned int f2bf2(float lo, float hi) {
    return (unsigned int)f2bf(lo) | ((unsigned int)f2bf(hi) << 16);
}
static __device__ __forceinline__ float bf2f(unsigned short s) {
    return __uint_as_float((unsigned int)s << 16);
}

// ---------------- W transpose + bf16 (+ fold q-scale) ----------------
__global__ __launch_bounds__(128) void wtrans_kernel(
    const float* __restrict__ Wq, const float* __restrict__ Wk,
    const float* __restrict__ Wv, unsigned short* __restrict__ Wt)
{
    const int w  = blockIdx.y;
    const float* W = (w == 0) ? Wq : (w == 1) ? Wk : Wv;
    const float sc = (w == 0) ? SCALE : 1.0f;
    unsigned short* dst = Wt + (size_t)w * 131072;
    const int n  = threadIdx.x;
    const int k0 = blockIdx.x * 64;
    for (int jc = 0; jc < 8; ++jc) {
        float v[8];
#pragma unroll
        for (int je = 0; je < 8; ++je)
            v[je] = W[(size_t)(k0 + jc * 8 + je) * HD + n] * sc;
        i32x4 p;
        p[0] = f2bf2(v[0], v[1]); p[1] = f2bf2(v[2], v[3]);
        p[2] = f2bf2(v[4], v[5]); p[3] = f2bf2(v[6], v[7]);
        *(i32x4*)&dst[(size_t)n * 1024 + k0 + jc * 8] = p;
    }
}

// ---------------- QKV projection via MFMA, 64x128 tiles ----------------
// grid (3, 256): x = which W, y = 64-row tile. 256 thr = 4 waves (2x2 of 32x64).
__global__ __launch_bounds__(256) void qkv_kernel(
    const float* __restrict__ x, const unsigned short* __restrict__ Wt,
    unsigned short* __restrict__ qb, unsigned short* __restrict__ kb,
    unsigned short* __restrict__ vtb)
{
    __shared__ unsigned short lds[64 * 72 + 128 * 72];   // 27648 B
    unsigned short* As = lds;              // x tile   64(m) x 64(k), pad 72
    unsigned short* Bs = lds + 64 * 72;    // Wt tile  128(n) x 64(k), pad 72

    const int w   = blockIdx.x;
    const int m0  = blockIdx.y * 64;
    const unsigned short* Wm = Wt + (size_t)w * 131072;
    const int t    = threadIdx.x;
    const int lane = t & 63, wv = t >> 6;
    const int quad = lane >> 4, l16 = lane & 15;
    const int mhalf = wv >> 1, nhalf = wv & 1;

    f32x4 acc[2][4];
#pragma unroll
    for (int i = 0; i < 2; ++i)
#pragma unroll
        for (int j = 0; j < 4; ++j) acc[i][j] = (f32x4){0.f, 0.f, 0.f, 0.f};

    for (int kt = 0; kt < EMB; kt += 64) {
        __syncthreads();
        // stage A: x fp32 -> bf16   (64x64)
#pragma unroll
        for (int i = 0; i < 2; ++i) {
            int g = t + 256 * i;           // 0..511
            int row = g >> 3, seg = g & 7;
            const float* px = &x[(size_t)(m0 + row) * EMB + kt + seg * 8];
            float4 a = *(const float4*)px;
            float4 b = *(const float4*)(px + 4);
            i32x4 p;
            p[0] = f2bf2(a.x, a.y); p[1] = f2bf2(a.z, a.w);
            p[2] = f2bf2(b.x, b.y); p[3] = f2bf2(b.z, b.w);
            *(i32x4*)&As[row * 72 + seg * 8] = p;
        }
        // stage B: Wt bf16 direct (128x64)
#pragma unroll
        for (int i = 0; i < 4; ++i) {
            int g = t + 256 * i;           // 0..1023
            int row = g >> 3, seg = g & 7;
            *(i32x4*)&Bs[row * 72 + seg * 8] =
                *(const i32x4*)&Wm[(size_t)row * 1024 + kt + seg * 8];
        }
        __syncthreads();
#pragma unroll
        for (int ks = 0; ks < 2; ++ks) {
            bf16x8 aA[2], aB[4];
#pragma unroll
            for (int mt = 0; mt < 2; ++mt)
                aA[mt] = *(const bf16x8*)&As[(mhalf * 32 + mt * 16 + l16) * 72 + ks * 32 + quad * 8];
#pragma unroll
            for (int nt = 0; nt < 4; ++nt)
                aB[nt] = *(const bf16x8*)&Bs[(nhalf * 64 + nt * 16 + l16) * 72 + ks * 32 + quad * 8];
#pragma unroll
            for (int mt = 0; mt < 2; ++mt)
#pragma unroll
                for (int nt = 0; nt < 4; ++nt)
                    acc[mt][nt] = __builtin_amdgcn_mfma_f32_16x16x32_bf16(
                        aA[mt], aB[nt], acc[mt][nt], 0, 0, 0);
        }
    }

    // epilogue: C -> LDS (layout per output), then coalesced copy out
    __syncthreads();
    unsigned short* Cs = lds;
    if (w < 2) {
        // natural [s][h], pad 136 (16B-aligned rows)
#pragma unroll
        for (int mt = 0; mt < 2; ++mt)
#pragma unroll
            for (int nt = 0; nt < 4; ++nt)
#pragma unroll
                for (int rr = 0; rr < 4; ++rr)
                    Cs[(mhalf * 32 + mt * 16 + quad * 4 + rr) * 136 +
                       nhalf * 64 + nt * 16 + l16] = f2bf(acc[mt][nt][rr]);
        __syncthreads();
        unsigned short* dst = ((w == 0) ? qb : kb) + (size_t)m0 * HD;
#pragma unroll
        for (int i = 0; i < 4; ++i) {
            int g = i * 256 + t;           // 0..1023
            int row = g >> 4, seg = g & 15;
            *(i32x4*)&dst[(size_t)row * 128 + seg * 8] = *(const i32x4*)&Cs[row * 136 + seg * 8];
        }
    } else {
        // transposed [h][s], pad 72
#pragma unroll
        for (int mt = 0; mt < 2; ++mt)
#pragma unroll
            for (int nt = 0; nt < 4; ++nt) {
                short4v p;
                p[0] = (short)f2bf(acc[mt][nt][0]); p[1] = (short)f2bf(acc[mt][nt][1]);
                p[2] = (short)f2bf(acc[mt][nt][2]); p[3] = (short)f2bf(acc[mt][nt][3]);
                *(short4v*)&Cs[(nhalf * 64 + nt * 16 + l16) * 72 +
                               mhalf * 32 + mt * 16 + quad * 4] = p;
            }
        __syncthreads();
        const int b = m0 >> 12, s0 = m0 & 4095;
#pragma unroll
        for (int i = 0; i < 4; ++i) {
            int g = i * 256 + t;           // 0..1023
            int h = g >> 3, seg = g & 7;
            *(i32x4*)&vtb[(size_t)b * (HD * SEQ) + (size_t)h * SEQ + s0 + seg * 8] =
                *(const i32x4*)&Cs[h * 72 + seg * 8];
        }
    }
}

// ---------------- Flash attention, split-KV (chunk=1024), S^T form ----------------
// Job = (b, qi 32-row tile, chunk c of 1024 kv). 320 jobs/batch -> grid (320, 4).
// 128 thr = 2 waves x 16 qrows. Writes unnormalized O (bf16) + m,l partials.
#define PADK 136   // 64 x 136 bf16
#define PADV 72    // 128 x 72 bf16
#define PADP 72    // 32 x 72 bf16

__global__ __launch_bounds__(128) void flash_kernel(
    const unsigned short* __restrict__ qb, const unsigned short* __restrict__ kb,
    const unsigned short* __restrict__ vtb, unsigned short* __restrict__ Opart,
    float* __restrict__ mbuf, float* __restrict__ lbuf)
{
    __shared__ unsigned short Ks[64 * PADK];
    __shared__ unsigned short Vt[128 * PADV];
    __shared__ unsigned short Pt[32 * PADP];

    const int t    = threadIdx.x;
    const int lane = t & 63, w = t >> 6;
    const int quad = lane >> 4, l16 = lane & 15;
    const int b    = blockIdx.y;

    // decode job -> (qi, c)
    const int j = blockIdx.x;
    int qi, c;
    if (j < 32)       { qi = j;                  c = 0; }
    else if (j < 96)  { qi = 32 + (j - 32) / 2;  c = (j - 32) & 1; }
    else if (j < 192) { qi = 64 + (j - 96) / 3;  c = (j - 96) % 3; }
    else              { qi = 96 + ((j - 192) >> 2); c = (j - 192) & 3; }

    const int qrow = qi * 32 + w * 16 + l16;
    const int jmax_total = (qi * 32 + 31) / 64 + 1;
    const int jbeg = c * 16;
    const int jend = min(jbeg + 16, jmax_total);

    bf16x8 qf[4];
    {
        const unsigned short* qp = qb + ((size_t)b * SEQ + qrow) * HD;
#pragma unroll
        for (int ks = 0; ks < 4; ++ks)
            qf[ks] = *(const bf16x8*)&qp[ks * 32 + quad * 8];
    }

    f32x4 O[8];
#pragma unroll
    for (int i = 0; i < 8; ++i) O[i] = (f32x4){0.f, 0.f, 0.f, 0.f};
    float m_run = -1e30f, l_run = 0.f;

    const unsigned short* kbb  = kb  + (size_t)b * SEQ * HD;
    const unsigned short* vtbb = vtb + (size_t)b * HD * SEQ;

    for (int j0 = jbeg; j0 < jend; ++j0) {
#pragma unroll
        for (int i = 0; i < 8; ++i) {
            int g = i * 128 + t;
            i32x4 kd = *(const i32x4*)&kbb[(size_t)j0 * 64 * HD + g * 8];
            *(i32x4*)&Ks[(g >> 4) * PADK + (g & 15) * 8] = kd;
        }
#pragma unroll
        for (int i = 0; i < 8; ++i) {
            int h = i * 16 + (t >> 3), s8 = t & 7;
            i32x4 vd = *(const i32x4*)&vtbb[(size_t)h * SEQ + j0 * 64 + s8 * 8];
            *(i32x4*)&Vt[h * PADV + s8 * 8] = vd;
        }
        __syncthreads();

        // ---- S^T = K . Q^T ----
        f32x4 st[4];
#pragma unroll
        for (int mt = 0; mt < 4; ++mt) {
            f32x4 a = (f32x4){0.f, 0.f, 0.f, 0.f};
#pragma unroll
            for (int ks = 0; ks < 4; ++ks) {
                bf16x8 kf = *(const bf16x8*)&Ks[(mt * 16 + l16) * PADK + ks * 32 + quad * 8];
                a = __builtin_amdgcn_mfma_f32_16x16x32_bf16(kf, qf[ks], a, 0, 0, 0);
            }
            st[mt] = a;
        }

        // ---- causal mask ----
        if (j0 * 64 + 63 > qi * 32 + w * 16) {
#pragma unroll
            for (int mt = 0; mt < 4; ++mt)
#pragma unroll
                for (int rr = 0; rr < 4; ++rr) {
                    int kv = j0 * 64 + mt * 16 + quad * 4 + rr;
                    if (kv > qrow) st[mt][rr] = -1e30f;
                }
        }

        // ---- online softmax ----
        float mx = -1e30f;
#pragma unroll
        for (int mt = 0; mt < 4; ++mt)
#pragma unroll
            for (int rr = 0; rr < 4; ++rr) mx = fmaxf(mx, st[mt][rr]);
        mx = fmaxf(mx, __shfl_xor(mx, 16));
        mx = fmaxf(mx, __shfl_xor(mx, 32));
        const float m_new = fmaxf(m_run, mx);
        const float alpha = __expf(m_run - m_new);
        float psum = 0.f;
#pragma unroll
        for (int mt = 0; mt < 4; ++mt)
#pragma unroll
            for (int rr = 0; rr < 4; ++rr) {
                float p = __expf(st[mt][rr] - m_new);
                st[mt][rr] = p;
                psum += p;
            }
        psum += __shfl_xor(psum, 16);
        psum += __shfl_xor(psum, 32);
        m_run = m_new;
        l_run = l_run * alpha + psum;

#pragma unroll
        for (int mt = 0; mt < 4; ++mt) {
            short4v p;
            p[0] = (short)f2bf(st[mt][0]); p[1] = (short)f2bf(st[mt][1]);
            p[2] = (short)f2bf(st[mt][2]); p[3] = (short)f2bf(st[mt][3]);
            *(short4v*)&Pt[(w * 16 + l16) * PADP + mt * 16 + quad * 4] = p;
        }

#pragma unroll
        for (int i = 0; i < 8; ++i) {
            O[i][0] *= alpha; O[i][1] *= alpha; O[i][2] *= alpha; O[i][3] *= alpha;
        }

        // ---- O^T += V^T . P^T ----
        bf16x8 pf0 = *(const bf16x8*)&Pt[(w * 16 + l16) * PADP + quad * 8];
        bf16x8 pf1 = *(const bf16x8*)&Pt[(w * 16 + l16) * PADP + 32 + quad * 8];
#pragma unroll
        for (int mt = 0; mt < 8; ++mt) {
            bf16x8 vf0 = *(const bf16x8*)&Vt[(mt * 16 + l16) * PADV + quad * 8];
            bf16x8 vf1 = *(const bf16x8*)&Vt[(mt * 16 + l16) * PADV + 32 + quad * 8];
            O[mt] = __builtin_amdgcn_mfma_f32_16x16x32_bf16(vf0, pf0, O[mt], 0, 0, 0);
            O[mt] = __builtin_amdgcn_mfma_f32_16x16x32_bf16(vf1, pf1, O[mt], 0, 0, 0);
        }
        __syncthreads();
    }

    // ---- partial epilogue: unnormalized O (bf16) + m,l ----
    const int r = w * 16 + l16;
    const size_t jobbase = ((size_t)b * NQT + qi) * MAXC + c;
    unsigned short* po = Opart + jobbase * (32 * 128) + (size_t)r * 128;
#pragma unroll
    for (int mt = 0; mt < 8; ++mt) {
        short4v p;
        p[0] = (short)f2bf(O[mt][0]); p[1] = (short)f2bf(O[mt][1]);
        p[2] = (short)f2bf(O[mt][2]); p[3] = (short)f2bf(O[mt][3]);
        *(short4v*)&po[mt * 16 + quad * 4] = p;
    }
    if (quad == 0) {
        mbuf[jobbase * 32 + r] = m_run;
        lbuf[jobbase * 32 + r] = l_run;
    }
}

// ---------------- Combine partials ----------------
// grid (128, 4), 128 thr. Each thread: one q-row x 32 head cols.
__global__ __launch_bounds__(128) void combine_kernel(
    const unsigned short* __restrict__ Opart, const float* __restrict__ mbuf,
    const float* __restrict__ lbuf, float* __restrict__ out)
{
    const int qi = blockIdx.x, b = blockIdx.y;
    const int nc = qi / 32 + 1;
    const int t = threadIdx.x;
    const int row = t >> 2, cg = (t & 3) * 32;
    const size_t base = ((size_t)b * NQT + qi) * MAXC;

    float mv[MAXC], lv[MAXC];
    float M = -1e30f;
    for (int c2 = 0; c2 < nc; ++c2) {
        mv[c2] = mbuf[(base + c2) * 32 + row];
        lv[c2] = lbuf[(base + c2) * 32 + row];
        M = fmaxf(M, mv[c2]);
    }
    float L = 0.f;
    for (int c2 = 0; c2 < nc; ++c2) L += __expf(mv[c2] - M) * lv[c2];
    const float Linv = 1.0f / L;

    float acc[32];
#pragma unroll
    for (int i = 0; i < 32; ++i) acc[i] = 0.f;
    for (int c2 = 0; c2 < nc; ++c2) {
        const float wgt = __expf(mv[c2] - M) * Linv;
        const unsigned short* po = Opart + (base + c2) * (32 * 128) + (size_t)row * 128 + cg;
#pragma unroll
        for (int i = 0; i < 4; ++i) {
            i32x4 d = *(const i32x4*)&po[i * 8];
#pragma unroll
            for (int e = 0; e < 4; ++e) {
                unsigned int u = (unsigned int)d[e];
                acc[i * 8 + e * 2]     = fmaf(wgt, bf2f((unsigned short)(u & 0xffff)), acc[i * 8 + e * 2]);
                acc[i * 8 + e * 2 + 1] = fmaf(wgt, bf2f((unsigned short)(u >> 16)),   acc[i * 8 + e * 2 + 1]);
            }
        }
    }
    float* op = out + ((size_t)b * SEQ + qi * 32 + row) * HD + cg;
#pragma unroll
    for (int i = 0; i < 8; ++i) {
        float4 res;
        res.x = acc[i * 4]; res.y = acc[i * 4 + 1];
        res.z = acc[i * 4 + 2]; res.w = acc[i * 4 + 3];
        *(float4*)&op[i * 4] = res;
    }
}

extern "C" void kernel_launch(void* const* d_in, const int* in_sizes, int n_in,
                              void* d_out, int out_size, void* d_ws, size_t ws_size,
                              hipStream_t stream) {
    const float* x  = (const float*)d_in[0];
    const float* Wq = (const float*)d_in[1];
    const float* Wk = (const float*)d_in[2];
    const float* Wv = (const float*)d_in[3];

    unsigned short* qb    = (unsigned short*)d_ws;          // [16384][128] bf16
    unsigned short* kb    = qb  + (size_t)MROWS * HD;       // [16384][128] bf16
    unsigned short* vtb   = kb  + (size_t)MROWS * HD;       // [4][128][4096] bf16
    unsigned short* Wt    = vtb + (size_t)MROWS * HD;       // [3][128][1024] bf16
    unsigned short* Opart = Wt  + (size_t)3 * HD * EMB;     // [4][128][4][32][128] bf16
    float* mbuf = (float*)(Opart + (size_t)BATCH * NQT * MAXC * 32 * 128);
    float* lbuf = mbuf + (size_t)BATCH * NQT * MAXC * 32;
    float* out = (float*)d_out;

    wtrans_kernel <<<dim3(16, 3),    dim3(128), 0, stream>>>(Wq, Wk, Wv, Wt);
    qkv_kernel    <<<dim3(3, 256),   dim3(256), 0, stream>>>(x, Wt, qb, kb, vtb);
    flash_kernel  <<<dim3(320, 4),   dim3(128), 0, stream>>>(qb, kb, vtb, Opart, mbuf, lbuf);
    combine_kernel<<<dim3(128, 4),   dim3(128), 0, stream>>>(Opart, mbuf, lbuf, out);
}